// Round 4
// baseline (18024.759 us; speedup 1.0000x reference)
//
#include <hip/hip_runtime.h>
#include <hip/hip_fp16.h>

#define B_ 128
#define T_ 512
#define E_ 128
#define D_ 128

// exp2(C2*x) == e^(2x);  L2E = log2(e)
#define C2f 2.885390081777927f
#define L2E 1.4426950408889634f

__device__ __forceinline__ float rcpf_(float x){ return __builtin_amdgcn_rcpf(x); }
__device__ __forceinline__ float ex2_(float x){ return __builtin_amdgcn_exp2f(x); }

__device__ __forceinline__ void gstoref(float* p, float v){
    __hip_atomic_store(p, v, __ATOMIC_RELAXED, __HIP_MEMORY_SCOPE_AGENT);
}
__device__ __forceinline__ float gloadf(const float* p){
    return __hip_atomic_load(p, __ATOMIC_RELAXED, __HIP_MEMORY_SCOPE_AGENT);
}
__device__ __forceinline__ void flag_set(int* p, int v){
    __hip_atomic_store(p, v, __ATOMIC_RELEASE, __HIP_MEMORY_SCOPE_AGENT);
}
__device__ __forceinline__ void flag_wait(int* p, int v){
    int it = 0;
    while (__hip_atomic_load(p, __ATOMIC_ACQUIRE, __HIP_MEMORY_SCOPE_AGENT) < v
           && it < (1 << 26)){ it++; __builtin_amdgcn_s_sleep(2); }
}

__global__ __launch_bounds__(256) void transpose_half(const float* __restrict__ in,
                                                      __half* __restrict__ out,
                                                      int K, int N){
    __shared__ float tile[32][33];
    int n0 = blockIdx.x * 32, k0 = blockIdx.y * 32;
    int tx = threadIdx.x & 31, ty = threadIdx.x >> 5;
    #pragma unroll
    for (int i = ty; i < 32; i += 8)
        tile[i][tx] = in[(size_t)(k0 + i) * N + n0 + tx];
    __syncthreads();
    #pragma unroll
    for (int i = ty; i < 32; i += 8)
        out[(size_t)(n0 + i) * K + k0 + tx] = __float2half(tile[tx][i]);
}

__global__ __launch_bounds__(256) void enc_to_half(const float* __restrict__ in,
                                                   __half* __restrict__ out){
    int i = (blockIdx.x * 256 + threadIdx.x) * 4;
    float4 v = *(const float4*)(in + i);
    *(__half2*)(out + i)     = __floats2half2_rn(v.x, v.y);
    *(__half2*)(out + i + 2) = __floats2half2_rn(v.z, v.w);
}

// P[b][n][t] = exp2(C2 * (sum_e enc[b][t][e]*Ua[e][n] + bu[n]))  as fp16
__global__ __launch_bounds__(256) void uenc_kernel(const float* __restrict__ enc,
                                                   const float* __restrict__ Ua,
                                                   const float* __restrict__ bu,
                                                   __half* __restrict__ P){
    int b = blockIdx.z;
    int t0 = blockIdx.x * 64;
    int n0 = blockIdx.y * 64;
    int tt = threadIdx.x & 63;
    int ng = threadIdx.x >> 6;
    const float* erow = enc + ((size_t)b * T_ + (t0 + tt)) * E_;
    const float* uap  = Ua + n0 + ng * 16;
    float acc[16];
    #pragma unroll
    for (int i = 0; i < 16; i++) acc[i] = 0.f;
    #pragma unroll 2
    for (int e0 = 0; e0 < E_; e0 += 4){
        float4 av = *(const float4*)(erow + e0);
        #pragma unroll
        for (int ee = 0; ee < 4; ee++){
            float a = (ee==0)?av.x:(ee==1)?av.y:(ee==2)?av.z:av.w;
            const float4* u4 = (const float4*)(uap + (size_t)(e0+ee) * T_);
            float4 x0 = u4[0], x1 = u4[1], x2 = u4[2], x3 = u4[3];
            acc[0]  = fmaf(a, x0.x, acc[0]);  acc[1]  = fmaf(a, x0.y, acc[1]);
            acc[2]  = fmaf(a, x0.z, acc[2]);  acc[3]  = fmaf(a, x0.w, acc[3]);
            acc[4]  = fmaf(a, x1.x, acc[4]);  acc[5]  = fmaf(a, x1.y, acc[5]);
            acc[6]  = fmaf(a, x1.z, acc[6]);  acc[7]  = fmaf(a, x1.w, acc[7]);
            acc[8]  = fmaf(a, x2.x, acc[8]);  acc[9]  = fmaf(a, x2.y, acc[9]);
            acc[10] = fmaf(a, x2.z, acc[10]); acc[11] = fmaf(a, x2.w, acc[11]);
            acc[12] = fmaf(a, x3.x, acc[12]); acc[13] = fmaf(a, x3.y, acc[13]);
            acc[14] = fmaf(a, x3.z, acc[14]); acc[15] = fmaf(a, x3.w, acc[15]);
        }
    }
    int nb = n0 + ng * 16;
    #pragma unroll
    for (int i = 0; i < 16; i++){
        float u = acc[i] + bu[nb + i];
        P[(size_t)b * T_ * T_ + (size_t)(nb + i) * T_ + t0 + tt] = __float2half(ex2_(C2f * u));
    }
}

__device__ __forceinline__ void dot8(float& acc, uint4 wv, float4 ha, float4 hb){
    float2 f0 = __half22float2(*reinterpret_cast<__half2*>(&wv.x));
    float2 f1 = __half22float2(*reinterpret_cast<__half2*>(&wv.y));
    float2 f2 = __half22float2(*reinterpret_cast<__half2*>(&wv.z));
    float2 f3 = __half22float2(*reinterpret_cast<__half2*>(&wv.w));
    acc = fmaf(ha.x, f0.x, acc); acc = fmaf(ha.y, f0.y, acc);
    acc = fmaf(ha.z, f1.x, acc); acc = fmaf(ha.w, f1.y, acc);
    acc = fmaf(hb.x, f2.x, acc); acc = fmaf(hb.y, f2.y, acc);
    acc = fmaf(hb.z, f3.x, acc); acc = fmaf(hb.w, f3.y, acc);
}

#define CVT2(u) __half22float2(*reinterpret_cast<const __half2*>(&(u)))

// grid: 256 linear blocks, remapped so partner blocks (b,0)/(b,1) are 8 apart
// (same XCD under round-robin dispatch). LDS ~156 KB -> 1 block/CU guaranteed.
__global__ __launch_bounds__(1024, 4) void decoder_kernel(
    const float* __restrict__ enc, const __half* __restrict__ enc_h, int use_f16,
    const float* __restrict__ labels,
    const float* __restrict__ init_h, const float* __restrict__ init_c,
    const float* __restrict__ Va,
    const float* __restrict__ ba, const float* __restrict__ bl,
    const float* __restrict__ Wc, const float* __restrict__ bc,
    const float* __restrict__ Wk,
    const float* __restrict__ W1, const float* __restrict__ b1,
    const float* __restrict__ W2, const float* __restrict__ b2,
    const __half* __restrict__ Wa_t, const __half* __restrict__ Wr_t,
    const __half* __restrict__ Pw,
    float* __restrict__ psbuf, float* __restrict__ cxbuf,
    int* __restrict__ fA, int* __restrict__ fB,
    float* __restrict__ out)
{
    __shared__ __align__(16) __half Plds[112 * 512];  // 112 KB LDS-resident P rows
    __shared__ __align__(16) float scratch[8192];     // 32 KB: B partials / C partials+dn
    __shared__ __align__(16) float Q_s[256];          // Q for own n-half
    __shared__ __align__(16) float Va2_s[256];        // -2*Va own n-half
    __shared__ __align__(16) float sc[512];           // own-half scores (all t)
    __shared__ __align__(16) float rz_s[512];         // h@Wr own-k-half partial
    __shared__ __align__(16) float hc_s[256];         // h,c
    __shared__ __align__(16) float ctx_s[128];
    __shared__ __align__(16) float bl_s[512], Wk_s[512];
    __shared__ float Wc_s[132];
    __shared__ float red[24];

    const int tid = threadIdx.x;
    // XCD-pair remap: lin = x + 8y; partner = lin +/- 8 (same lin%8)
    const int lin = blockIdx.x;
    const int x_ = lin & 7, y_ = lin >> 3;
    const int h_ = y_ & 1;
    const int b  = x_ * 16 + (y_ >> 1);

    if (tid < 128){
        hc_s[tid]       = init_h[b*128 + tid];
        hc_s[128 + tid] = init_c[b*128 + tid];
    }
    if (tid < 256) Va2_s[tid] = -2.f * Va[256*h_ + tid];
    if (tid < 512){ bl_s[tid] = bl[tid]; Wk_s[tid] = Wk[tid]; }
    if (tid < 129) Wc_s[tid] = Wc[tid];
    if (tid == 129) Wc_s[130] = bc[0];

    const __half* Pb = Pw + ((size_t)b * T_ + 256 * h_) * T_;   // own n-half rows

    // Fill LDS P rows: lds row r = 7g + j  <->  n_loc = 16g + j (j<7)
    {
        int wid = tid >> 6, lane = tid & 63;
        for (int r = wid; r < 112; r += 16){
            int g = r / 7, j = r - 7 * g;
            *((uint4*)Plds + (size_t)r * 64 + lane) =
                *((const uint4*)(Pb + (size_t)(16*g + j) * 512) + lane);
        }
    }
    __syncthreads();

    int* myfA = &fA[b*2 + h_];   int* pfA = &fA[b*2 + (1 - h_)];
    int* myfB = &fB[b*2 + h_];   int* pfB = &fB[b*2 + (1 - h_)];
    const float4* hc4 = (const float4*)hc_s;

    for (int t = 0; t < T_; t++){
        const int par = t & 1;
        // pslot: [0,256) scores for partner's t-half, [256,768) rz k-half partial
        float* psme = psbuf + ((size_t)par * 256 + b*2 + h_)     * 1024;
        float* pspr = psbuf + ((size_t)par * 256 + b*2 + (1-h_)) * 1024;
        float* cxme = cxbuf + ((size_t)par * 256 + b*2 + h_)     * 132;
        float* cxpr = cxbuf + ((size_t)par * 256 + b*2 + (1-h_)) * 132;

        // ---- phase A: s-partials (own n-half, k split 2-way) ; rz own-k-half
        if (tid < 512){
            int n = tid & 255, kh = tid >> 8;
            float acc = 0.f;
            const uint4* wa = (const uint4*)(Wa_t + (size_t)(256*h_ + n) * 256 + kh * 128);
            #pragma unroll 4
            for (int i = 0; i < 16; i++)
                dot8(acc, wa[i], hc4[kh*32 + 2*i], hc4[kh*32 + 2*i + 1]);
            scratch[kh*256 + n] = acc;
        } else {
            int m = tid - 512;
            float acc = 0.f;
            const uint4* wr = (const uint4*)(Wr_t + (size_t)m * 128 + 64 * h_);
            #pragma unroll 4
            for (int i = 0; i < 8; i++)
                dot8(acc, wr[i], hc4[16*h_ + 2*i], hc4[16*h_ + 2*i + 1]);
            rz_s[m] = acc;
        }
        __syncthreads();                                         // b1
        // ---- combine: Q = exp2(C2*s) ; publish rz partial (piggyback on hs1)
        if (tid < 256){
            float s = scratch[tid] + scratch[256 + tid] + ba[256*h_ + tid];
            Q_s[tid] = ex2_(C2f * s);
        } else if (tid >= 512){
            int m = tid - 512;
            gstoref(psme + 256 + m, rz_s[m]);
        }
        __syncthreads();                                         // b2

        // ---- phase B: own-half score partials; 7 LDS + 9 global rows per 16-n group
        {
            int ql = tid & 63, g = tid >> 6;
            const int nb = 16 * g;
            float acc[8];
            #pragma unroll
            for (int k = 0; k < 8; k++) acc[k] = 0.f;
            #pragma unroll
            for (int quad = 0; quad < 4; quad++){
                uint4 pv0, pv1, pv2, pv3;
                {
                    int j0 = quad*4;
                    pv0 = (j0+0 < 7) ? *((const uint4*)Plds + (size_t)(7*g + j0+0)*64 + ql)
                                     : *((const uint4*)Pb + (size_t)(nb + j0+0)*64 + ql);
                    pv1 = (j0+1 < 7) ? *((const uint4*)Plds + (size_t)(7*g + j0+1)*64 + ql)
                                     : *((const uint4*)Pb + (size_t)(nb + j0+1)*64 + ql);
                    pv2 = (j0+2 < 7) ? *((const uint4*)Plds + (size_t)(7*g + j0+2)*64 + ql)
                                     : *((const uint4*)Pb + (size_t)(nb + j0+2)*64 + ql);
                    pv3 = (j0+3 < 7) ? *((const uint4*)Plds + (size_t)(7*g + j0+3)*64 + ql)
                                     : *((const uint4*)Pb + (size_t)(nb + j0+3)*64 + ql);
                }
                float q0 = Q_s[nb + quad*4 + 0], q1 = Q_s[nb + quad*4 + 1];
                float q2 = Q_s[nb + quad*4 + 2], q3 = Q_s[nb + quad*4 + 3];
                float a0 = Va2_s[nb + quad*4 + 0], a1 = Va2_s[nb + quad*4 + 1];
                float a2 = Va2_s[nb + quad*4 + 2], a3 = Va2_s[nb + quad*4 + 3];
                float2 A0 = CVT2(pv0.x), A1 = CVT2(pv0.y), A2 = CVT2(pv0.z), A3 = CVT2(pv0.w);
                float2 B0 = CVT2(pv1.x), B1 = CVT2(pv1.y), B2 = CVT2(pv1.z), B3 = CVT2(pv1.w);
                float2 C0 = CVT2(pv2.x), C1 = CVT2(pv2.y), C2 = CVT2(pv2.z), C3 = CVT2(pv2.w);
                float2 D0 = CVT2(pv3.x), D1 = CVT2(pv3.y), D2 = CVT2(pv3.z), D3 = CVT2(pv3.w);
                #define TREE(e0,e1,e2,e3,K) { \
                    float d0 = fmaf(e0, q0, 1.f), d1 = fmaf(e1, q1, 1.f); \
                    float d2 = fmaf(e2, q2, 1.f), d3 = fmaf(e3, q3, 1.f); \
                    float n01 = fmaf(a0, d1, a1*d0), d01 = d0*d1; \
                    float n23 = fmaf(a2, d3, a3*d2), d23 = d2*d3; \
                    acc[K] = fmaf(fmaf(n01, d23, n23*d01), rcpf_(d01*d23), acc[K]); }
                TREE(A0.x, B0.x, C0.x, D0.x, 0); TREE(A0.y, B0.y, C0.y, D0.y, 1);
                TREE(A1.x, B1.x, C1.x, D1.x, 2); TREE(A1.y, B1.y, C1.y, D1.y, 3);
                TREE(A2.x, B2.x, C2.x, D2.x, 4); TREE(A2.y, B2.y, C2.y, D2.y, 5);
                TREE(A3.x, B3.x, C3.x, D3.x, 6); TREE(A3.y, B3.y, C3.y, D3.y, 7);
                #undef TREE
            }
            float4* o = (float4*)(scratch + g*512 + ql*8);
            o[0] = make_float4(acc[0], acc[1], acc[2], acc[3]);
            o[1] = make_float4(acc[4], acc[5], acc[6], acc[7]);
        }
        __syncthreads();                                         // b3
        // ---- B-reduce -> sc (own-half score, all t); publish partner's t-half
        if (tid < 512){
            float v = 0.f;
            #pragma unroll
            for (int g = 0; g < 16; g++) v += scratch[g*512 + tid];
            sc[tid] = v;
            int off = 256 * (1 - h_);
            if (tid >= off && tid < off + 256) gstoref(psme + (tid - off), v);
        }
        __syncthreads();                                         // b4
        if (tid == 0){ flag_set(myfA, t + 1); flag_wait(pfA, t + 1); }
        __syncthreads();                                         // b5

        // ---- phase C (p fused): own t-half ctx partials + denom partials
        {
            int eq = tid & 31, tg = tid >> 5;
            int row0 = 256*h_ + tg*8;
            float p[8]; float psum = 0.f;
            #pragma unroll
            for (int i = 0; i < 8; i++){
                float sco = sc[row0 + i] + gloadf(pspr + tg*8 + i);
                p[i] = ex2_(sco * L2E);
                psum += p[i];
            }
            float4 acc4 = make_float4(0.f, 0.f, 0.f, 0.f);
            if (use_f16){
                const uint2* ep = (const uint2*)(enc_h + ((size_t)b*T_ + row0)*E_) + eq;
                #pragma unroll
                for (int i = 0; i < 8; i++){
                    uint2 ev = ep[(size_t)i * 32];
                    float2 e01 = __half22float2(*reinterpret_cast<__half2*>(&ev.x));
                    float2 e23 = __half22float2(*reinterpret_cast<__half2*>(&ev.y));
                    acc4.x = fmaf(p[i], e01.x, acc4.x); acc4.y = fmaf(p[i], e01.y, acc4.y);
                    acc4.z = fmaf(p[i], e23.x, acc4.z); acc4.w = fmaf(p[i], e23.y, acc4.w);
                }
            } else {
                const float4* ep = (const float4*)(enc + ((size_t)b*T_ + row0)*E_) + eq;
                #pragma unroll
                for (int i = 0; i < 8; i++){
                    float4 ev = ep[(size_t)i * 32];
                    acc4.x = fmaf(p[i], ev.x, acc4.x); acc4.y = fmaf(p[i], ev.y, acc4.y);
                    acc4.z = fmaf(p[i], ev.z, acc4.z); acc4.w = fmaf(p[i], ev.w, acc4.w);
                }
            }
            *(float4*)(scratch + tg*128 + eq*4) = acc4;
            if (eq == 0) scratch[4096 + tg] = psum;
        }
        __syncthreads();                                         // b6
        // ---- C-reduce: own ctx partial + own denom; publish both
        if (tid < 128){
            float s = 0.f;
            #pragma unroll
            for (int tg = 0; tg < 32; tg++) s += scratch[tg*128 + tid];
            ctx_s[tid] = s;
            gstoref(cxme + tid, s);
        } else if (tid < 160){
            float v = scratch[4096 + (tid - 128)];
            #pragma unroll
            for (int off = 16; off; off >>= 1) v += __shfl_down(v, off);
            if (tid == 128){ red[2] = v; gstoref(cxme + 128, v); }
        }
        __syncthreads();                                         // b7
        if (tid == 0){ flag_set(myfB, t + 1); flag_wait(pfB, t + 1); }
        __syncthreads();                                         // b8

        // ---- combine ctx + y partials; prefetch partner rz + label
        float rp0 = 0.f, rp1 = 0.f, rp2 = 0.f, rp3 = 0.f, labv = 0.f;
        if (tid < 128){
            rp0 = gloadf(pspr + 256 + tid);
            rp1 = gloadf(pspr + 256 + 128 + tid);
            rp2 = gloadf(pspr + 256 + 256 + tid);
            rp3 = gloadf(pspr + 256 + 384 + tid);
            labv = labels[(size_t)b * T_ + t];
            float dn = red[2] + gloadf(cxpr + 128);
            float ctxv = (ctx_s[tid] + gloadf(cxpr + tid)) * rcpf_(dn);
            ctx_s[tid] = ctxv;
            float yp = ctxv * Wc_s[1 + tid];
            #pragma unroll
            for (int off = 32; off; off >>= 1) yp += __shfl_xor(yp, off);
            if ((tid & 63) == 0) red[16 + (tid >> 6)] = yp;
        }
        __syncthreads();                                         // b9
        // ---- gates (Keras i,f,g,o), update h,c  (duplicated in both blocks)
        if (tid < 128){
            float y = fmaf(labv, Wc_s[0], red[16] + red[17] + Wc_s[130]);
            float zi = rz_s[tid]       + rp0 + bl_s[tid]       + y * Wk_s[tid];
            float zf = rz_s[128 + tid] + rp1 + bl_s[128 + tid] + y * Wk_s[128 + tid];
            float zg = rz_s[256 + tid] + rp2 + bl_s[256 + tid] + y * Wk_s[256 + tid];
            float zo = rz_s[384 + tid] + rp3 + bl_s[384 + tid] + y * Wk_s[384 + tid];
            float si = rcpf_(1.f + ex2_(-L2E * zi));
            float sf = rcpf_(1.f + ex2_(-L2E * zf));
            float so = rcpf_(1.f + ex2_(-L2E * zo));
            float tg_ = 1.f - 2.f * rcpf_(ex2_(C2f * zg) + 1.f);
            float cn = sf * hc_s[128 + tid] + si * tg_;
            float tc = 1.f - 2.f * rcpf_(ex2_(C2f * cn) + 1.f);
            hc_s[128 + tid] = cn;
            hc_s[tid] = so * tc;
        }
        __syncthreads();                                         // b10
    }

    // ---- epilogue: pred = ([h, ctx] @ W1 + b1) @ W2 + b2   (h_==0 writes)
    if (tid < 128){
        float acc = b1[tid];
        for (int k = 0; k < 128; k++) acc = fmaf(hc_s[k],  W1[k*128 + tid], acc);
        for (int k = 0; k < 128; k++) acc = fmaf(ctx_s[k], W1[(128+k)*128 + tid], acc);
        scratch[tid] = acc * W2[tid];
    }
    __syncthreads();
    if (h_ == 0 && tid < 64){
        float a = scratch[tid] + scratch[64 + tid];
        #pragma unroll
        for (int off = 32; off; off >>= 1) a += __shfl_xor(a, off);
        if (tid == 0) out[b] = a + b2[0];
    }
}

extern "C" void kernel_launch(void* const* d_in, const int* in_sizes, int n_in,
                              void* d_out, int out_size, void* d_ws, size_t ws_size,
                              hipStream_t stream){
    const float* enc      = (const float*)d_in[0];
    const float* labels   = (const float*)d_in[1];
    const float* init_h   = (const float*)d_in[2];
    const float* init_c   = (const float*)d_in[3];
    const float* Wa = (const float*)d_in[5];
    const float* ba = (const float*)d_in[6];
    const float* Ua = (const float*)d_in[7];
    const float* bu = (const float*)d_in[8];
    const float* Va = (const float*)d_in[9];
    // d_in[10] = bv: softmax-shift-invariant, unused
    const float* Wc = (const float*)d_in[11];
    const float* bc = (const float*)d_in[12];
    const float* Wk = (const float*)d_in[13];
    const float* Wr = (const float*)d_in[14];
    const float* bl = (const float*)d_in[15];
    const float* W1 = (const float*)d_in[16];
    const float* b1 = (const float*)d_in[17];
    const float* W2 = (const float*)d_in[18];
    const float* b2 = (const float*)d_in[19];

    char* ws = (char*)d_ws;
    const size_t szP   = (size_t)B_ * T_ * T_ * 2;     // 67,108,864
    const size_t szWa  = 512 * 256 * 2;                // 262,144
    const size_t szWr  = 512 * 128 * 2;                // 131,072
    const size_t base  = szP + szWa + szWr;
    const size_t szEnc = (size_t)B_ * T_ * E_ * 2;     // 16,777,216
    const size_t szPs  = (size_t)2 * 256 * 1024 * 4;   // 2,097,152
    const size_t szCx  = (size_t)2 * 256 * 132 * 4;    // 540,672
    const size_t commSz = szPs + szCx + 512 * 4;

    __half* P    = (__half*)ws;
    __half* Wa_t = (__half*)(ws + szP);
    __half* Wr_t = (__half*)(ws + szP + szWa);

    int use_f16 = (ws_size >= base + szEnc + commSz) ? 1 : 0;
    __half* enc_h = (__half*)(ws + base);
    size_t comm0 = use_f16 ? (base + szEnc) : base;
    float* psbuf = (float*)(ws + comm0);
    float* cxbuf = psbuf + 2 * 256 * 1024;
    int*   flags = (int*)(cxbuf + 2 * 256 * 132);
    int* fA = flags;           // [128][2]
    int* fB = flags + 256;     // [128][2]

    hipMemsetAsync(flags, 0, 512 * sizeof(int), stream);

    transpose_half<<<dim3(16, 8, 1), 256, 0, stream>>>(Wa, Wa_t, 256, 512);
    transpose_half<<<dim3(16, 4, 1), 256, 0, stream>>>(Wr, Wr_t, 128, 512);
    if (use_f16)
        enc_to_half<<<8192, 256, 0, stream>>>(enc, enc_h);

    dim3 g1(T_/64, T_/64, B_);
    uenc_kernel<<<g1, 256, 0, stream>>>(enc, Ua, bu, P);

    decoder_kernel<<<256, 1024, 0, stream>>>(enc, enc_h, use_f16,
        labels, init_h, init_c, Va, ba, bl, Wc, bc, Wk, W1, b1, W2, b2,
        Wa_t, Wr_t, P, psbuf, cxbuf, fA, fB, (float*)d_out);
}